// Round 8
// baseline (1548.465 us; speedup 1.0000x reference)
//
#include <hip/hip_runtime.h>
#include <math.h>

#define NPTS 8192
#define NB 2
#define FDIM 96
#define KNN 20
#define VN_EPS 1e-6f
#define VN_BN_EPS 1e-5f
#define CPT 10              // candidates per 256-col tile
#define CROW (32 * CPT)     // 320 candidates per row

typedef float f32x16 __attribute__((ext_vector_type(16)));
typedef _Float16 f16x8 __attribute__((ext_vector_type(8)));
typedef unsigned short u16x8 __attribute__((ext_vector_type(8)));

// drain LDS ops + compiler barrier (waves independent; no cross-wave sync needed)
#define WAVESYNC()                                            \
    do {                                                      \
        asm volatile("s_waitcnt lgkmcnt(0)" ::: "memory");    \
        __builtin_amdgcn_wave_barrier();                      \
        asm volatile("" ::: "memory");                        \
    } while (0)

// ---------------- Kernel 1: xx = sum_f xf^2  AND  xs = f16 split table ----------------
__global__ __launch_bounds__(256) void k_prep(const float* __restrict__ x,
                                              float* __restrict__ xx,
                                              unsigned short* __restrict__ xs) {
    int m = blockIdx.x * 256 + threadIdx.x;
    int b = m >> 13, n = m & 8191;
    const float* xf = x + (size_t)b * FDIM * NPTS;
    unsigned short* row = xs + (size_t)m * 192;
    float s = 0.f;
    for (int fc = 0; fc < 12; ++fc) {
        u16x8 hv, lv;
        #pragma unroll
        for (int j = 0; j < 8; ++j) {
            float vv = xf[(size_t)(fc * 8 + j) * NPTS + n];
            s += vv * vv;
            _Float16 h = (_Float16)vv;
            float hf = (float)h;
            _Float16 l = (_Float16)(vv - hf);
            union { _Float16 f; unsigned short u; } ch, cl;
            ch.f = h; cl.f = l;
            hv[j] = ch.u; lv[j] = cl.u;
        }
        *(u16x8*)(row + fc * 8) = hv;
        *(u16x8*)(row + 96 + fc * 8) = lv;
    }
    xx[m] = s;
}

// ---------------- Kernel 2: fused neg-dist MFMA + per-tile top-10 candidates ----------------
// Wave = 32 rows x 256 cols (acc[8] 32x32 tiles). 3-pass f16 split: (hA+lA)*hB on Bh, hA*lB on Bl.
// Epilogue: per row, top-10 of this 256-col tile (exact val-desc/col-asc order) -> candV/candC.
// No distance matrix is ever written to memory.
__global__ __launch_bounds__(256, 2) void k_distc(const unsigned short* __restrict__ xs,
                                                  const float* __restrict__ xx,
                                                  float* __restrict__ candV,
                                                  int* __restrict__ candC) {
    __shared__ __align__(16) unsigned short Bsl[256][104];
    __shared__ float sxr[128];
    __shared__ float sxc[256];
    int t = threadIdx.x;
    int lane = t & 63, wid = t >> 6;
    int l31 = lane & 31, hi = lane >> 5;
    int r0p = blockIdx.x * 128;                  // global row-panel base (0..16256)
    int b = r0p >> 13;
    int cb = blockIdx.y * 256;                   // col base within batch
    const unsigned short* xsb = xs + (size_t)b * NPTS * 192;
    int n0 = (r0p & 8191) + wid * 32;            // wave's row base within batch

    // A-fragments register-resident (rows on l31, K-half on hi) — validated layout
    f16x8 afh[6], afl[6];
    const unsigned short* arow = xsb + (size_t)(n0 + l31) * 192 + hi * 8;
    #pragma unroll
    for (int ks = 0; ks < 6; ++ks) {
        afh[ks] = *(const f16x8*)(arow + ks * 16);
        afl[ks] = *(const f16x8*)(arow + 96 + ks * 16);
    }

    if (t < 128) sxr[t] = xx[r0p + t];
    sxc[t] = xx[(b << 13) + cb + t];

    f32x16 acc[8];
    #pragma unroll
    for (int ct = 0; ct < 8; ++ct)
        #pragma unroll
        for (int e = 0; e < 16; ++e) acc[ct][e] = 0.f;

    {   // stage B hi
        const unsigned short* sb = xsb + (size_t)(cb + t) * 192;
        #pragma unroll
        for (int j = 0; j < 12; ++j) *(u16x8*)(&Bsl[t][j * 8]) = *(const u16x8*)(sb + j * 8);
    }
    __syncthreads();
    #pragma unroll
    for (int ks = 0; ks < 6; ++ks)
        #pragma unroll
        for (int ct = 0; ct < 8; ++ct) {
            f16x8 bf = *(const f16x8*)&Bsl[ct * 32 + l31][ks * 16 + hi * 8];
            acc[ct] = __builtin_amdgcn_mfma_f32_32x32x16_f16(afh[ks], bf, acc[ct], 0, 0, 0);
            acc[ct] = __builtin_amdgcn_mfma_f32_32x32x16_f16(afl[ks], bf, acc[ct], 0, 0, 0);
        }
    __syncthreads();
    {   // stage B lo
        const unsigned short* sb = xsb + (size_t)(cb + t) * 192 + 96;
        #pragma unroll
        for (int j = 0; j < 12; ++j) *(u16x8*)(&Bsl[t][j * 8]) = *(const u16x8*)(sb + j * 8);
    }
    __syncthreads();
    #pragma unroll
    for (int ks = 0; ks < 6; ++ks)
        #pragma unroll
        for (int ct = 0; ct < 8; ++ct) {
            f16x8 bf = *(const f16x8*)&Bsl[ct * 32 + l31][ks * 16 + hi * 8];
            acc[ct] = __builtin_amdgcn_mfma_f32_32x32x16_f16(afh[ks], bf, acc[ct], 0, 0, 0);
        }

    // ---- per-row top-10 extraction (two rows in parallel: one per hi-group) ----
    float xc[8];
    #pragma unroll
    for (int ct = 0; ct < 8; ++ct) xc[ct] = sxc[ct * 32 + l31];

    #pragma unroll
    for (int q = 0; q < 4; ++q) {
        #pragma unroll
        for (int rr = 0; rr < 4; ++rr) {
            int rowin = wid * 32 + 4 * hi + 8 * q + rr;      // block-local row
            float xr = sxr[rowin];
            float val[8];
            #pragma unroll
            for (int ct = 0; ct < 8; ++ct)
                val[ct] = 2.f * acc[ct][q * 4 + rr] - xr - xc[ct];
            unsigned msk = 0u;
            size_t obase = (size_t)(r0p + rowin) * CROW + (size_t)blockIdx.y * CPT;
            #pragma unroll
            for (int j = 0; j < CPT; ++j) {
                float bv = -3.4e38f; int bc = 0x7fffffff;
                #pragma unroll
                for (int ct = 0; ct < 8; ++ct) {
                    if (!((msk >> ct) & 1u)) {
                        int cg = cb + ct * 32 + l31;
                        if (val[ct] > bv || (val[ct] == bv && cg < bc)) { bv = val[ct]; bc = cg; }
                    }
                }
                #pragma unroll
                for (int off = 1; off < 32; off <<= 1) {
                    float ov = __shfl_xor(bv, off);
                    int oc = __shfl_xor(bc, off);
                    if (ov > bv || (ov == bv && oc < bc)) { bv = ov; bc = oc; }
                }
                if ((bc & 31) == l31) msk |= 1u << ((bc >> 5) & 7);   // winner lane marks its slot
                if (l31 == j) { candV[obase + j] = bv; candC[obase + j] = bc; }
            }
        }
    }
}

// ---------------- Kernel 3: merge 320 candidates -> top-20 per row (one wave/row) ----------------
__global__ __launch_bounds__(256) void k_mrg(const float* __restrict__ candV,
                                             const int* __restrict__ candC,
                                             int* __restrict__ idxOut) {
    int t = threadIdx.x;
    int lane = t & 63, wid = t >> 6;
    int row = blockIdx.x * 4 + wid;
    const float* cv = candV + (size_t)row * CROW;
    const int* cc = candC + (size_t)row * CROW;
    float v[5]; int c[5];
    #pragma unroll
    for (int i = 0; i < 5; ++i) { v[i] = cv[lane + 64 * i]; c[i] = cc[lane + 64 * i]; }
    unsigned msk = 0u;
    for (int kk = 0; kk < KNN; ++kk) {
        float bv = -3.4e38f; int bc = 0x7fffffff;
        #pragma unroll
        for (int i = 0; i < 5; ++i) {
            if (!((msk >> i) & 1u)) {
                if (v[i] > bv || (v[i] == bv && c[i] < bc)) { bv = v[i]; bc = c[i]; }
            }
        }
        #pragma unroll
        for (int off = 1; off < 64; off <<= 1) {
            float ov = __shfl_xor(bv, off);
            int oc = __shfl_xor(bc, off);
            if (ov > bv || (ov == bv && oc < bc)) { bv = ov; bc = oc; }
        }
        if (lane == 0) idxOut[(size_t)row * KNN + kk] = bc;
        #pragma unroll
        for (int i = 0; i < 5; ++i)
            if (c[i] == bc) msk |= 1u << i;     // cols unique per row -> exactly one match
    }
}

// ---------------- Kernel 4: u = A*x_point, v = (B-A)*x_point ----------------
__global__ __launch_bounds__(256) void k_uv(const float* __restrict__ x,
                                            const float* __restrict__ W1,
                                            float* __restrict__ u,
                                            float* __restrict__ v) {
    __shared__ float sA[64 * 33];
    __shared__ float sV[64 * 33];
    __shared__ float sxf[FDIM * 16];
    int t = threadIdx.x;
    for (int i = t; i < 64 * 32; i += 256) {
        int o = i >> 5, c = i & 31;
        float a = W1[o * 64 + c];
        sA[o * 33 + c] = a;
        sV[o * 33 + c] = W1[o * 64 + 32 + c] - a;
    }
    int p0 = blockIdx.x * 16;
    int b = p0 >> 13, nb = p0 & 8191;
    const float* xf = x + (size_t)b * FDIM * NPTS;
    for (int i = t; i < FDIM * 16; i += 256) {
        int f = i >> 4, p = i & 15;
        sxf[f * 16 + p] = xf[(size_t)f * NPTS + nb + p];
    }
    __syncthreads();
    #pragma unroll
    for (int ii = 0; ii < 4; ++ii) {
        int it = t + 256 * ii;
        int o = it & 63, p = it >> 6;
        float u0 = 0.f, u1 = 0.f, u2 = 0.f, w0 = 0.f, w1 = 0.f, w2 = 0.f;
        #pragma unroll
        for (int c = 0; c < 32; ++c) {
            float a = sA[o * 33 + c];
            float wv = sV[o * 33 + c];
            float x0 = sxf[(c * 3 + 0) * 16 + p];
            float x1 = sxf[(c * 3 + 1) * 16 + p];
            float x2 = sxf[(c * 3 + 2) * 16 + p];
            u0 += a * x0;  u1 += a * x1;  u2 += a * x2;
            w0 += wv * x0; w1 += wv * x1; w2 += wv * x2;
        }
        size_t base = ((size_t)(p0 + p) * 64 + o) * 3;
        u[base] = u0; u[base + 1] = u1; u[base + 2] = u2;
        v[base] = w0; v[base + 1] = w1; v[base + 2] = w2;
    }
}

// ---------------- Kernel 5: BN stats partials ----------------
__global__ __launch_bounds__(256) void k_stats(const float* __restrict__ u,
                                               const float* __restrict__ v,
                                               const int* __restrict__ idx,
                                               float* __restrict__ partial) {
    int blk = blockIdx.x, t = threadIdx.x;
    int o = t & 63, sub = t >> 6;
    int p0 = blk * 8;
    __shared__ float svf[8 * 192];
    __shared__ int sjf[8 * KNN];
    for (int i = t; i < 8 * 192; i += 256) svf[i] = v[(size_t)p0 * 192 + i];
    for (int i = t; i < 8 * KNN; i += 256) sjf[i] = idx[(size_t)p0 * KNN + i];
    __syncthreads();
    float s1 = 0.f, s2 = 0.f;
    for (int p = 0; p < 8; ++p) {
        int gpt = p0 + p;
        size_t ubase = (size_t)(gpt >> 13) * NPTS * 192;
        const float* vp = &svf[p * 192 + o * 3];
        float v0 = vp[0], v1 = vp[1], v2 = vp[2];
        for (int kk = sub; kk < KNN; kk += 4) {
            int j = sjf[p * KNN + kk];
            const float* up = u + ubase + (size_t)j * 192 + o * 3;
            float q0 = up[0] + v0, q1 = up[1] + v1, q2 = up[2] + v2;
            float nrm = sqrtf(q0 * q0 + q1 * q1 + q2 * q2) + VN_EPS;
            s1 += nrm;
            s2 += nrm * nrm;
        }
    }
    __shared__ float r1[256], r2[256];
    r1[t] = s1; r2[t] = s2;
    __syncthreads();
    if (t < 64) {
        float a1 = r1[t] + r1[t + 64] + r1[t + 128] + r1[t + 192];
        float a2 = r2[t] + r2[t + 64] + r2[t + 128] + r2[t + 192];
        partial[(size_t)blk * 128 + t] = a1;
        partial[(size_t)blk * 128 + 64 + t] = a2;
    }
}

// ---------------- Kernel 6: reduce stats -> gs, bs ----------------
__global__ __launch_bounds__(256) void k_reduce(const float* __restrict__ partial,
                                                const float* __restrict__ gamma,
                                                const float* __restrict__ beta,
                                                float* __restrict__ gsbs) {
    int ch = blockIdx.x, t = threadIdx.x;
    float s1 = 0.f, s2 = 0.f;
    for (int i = t; i < 2048; i += 256) {
        s1 += partial[(size_t)i * 128 + ch];
        s2 += partial[(size_t)i * 128 + 64 + ch];
    }
    __shared__ float r1[256], r2[256];
    r1[t] = s1; r2[t] = s2;
    __syncthreads();
    for (int s = 128; s > 0; s >>= 1) {
        if (t < s) { r1[t] += r1[t + s]; r2[t] += r2[t + s]; }
        __syncthreads();
    }
    if (t == 0) {
        const float cnt = (float)(NB * NPTS * KNN);
        float mean = r1[0] / cnt;
        float var = r2[0] / cnt - mean * mean;
        float inv = 1.0f / sqrtf(var + VN_BN_EPS);
        float g = gamma[ch] * inv;
        gsbs[ch] = g;
        gsbs[64 + ch] = beta[ch] - mean * g;
    }
}

// ---------------- Kernel 7: fused BN + VN-LeakyReLU + mean, MFMA matvec ----------------
__global__ __launch_bounds__(256) void k_final(const float* __restrict__ u,
                                               const float* __restrict__ v,
                                               const int* __restrict__ idx,
                                               const float* __restrict__ Wd,
                                               const float* __restrict__ gsbs,
                                               float* __restrict__ out) {
    int t = threadIdx.x;
    int lane = t & 63, w = t >> 6;
    int l31 = lane & 31, hi = lane >> 5;
    int gpt = blockIdx.x * 4 + w;                 // global point b*N+n
    int b = gpt >> 13, n = gpt & 8191;

    __shared__ __align__(16) unsigned short Qls[4][30 * 72];  // f16
    __shared__ __align__(16) float Dls[4][30 * 64];           // f32
    unsigned short* Qw = Qls[w];
    float* Dw = Dls[w];

    f16x8 Bf[2][4];
    #pragma unroll
    for (int ct = 0; ct < 2; ++ct)
        #pragma unroll
        for (int ks = 0; ks < 4; ++ks) {
            const float* wp = Wd + (size_t)(ct * 32 + l31) * 64 + ks * 16 + hi * 8;
            f16x8 f;
            #pragma unroll
            for (int jj = 0; jj < 8; ++jj) f[jj] = (_Float16)wp[jj];
            Bf[ct][ks] = f;
        }

    float gso = gsbs[lane], bso = gsbs[64 + lane];
    size_t vb = (size_t)gpt * 192 + lane * 3;
    float v0 = v[vb], v1 = v[vb + 1], v2 = v[vb + 2];
    const int* jrow = idx + (size_t)gpt * KNN;
    size_t ubase = (size_t)b * NPTS * 192;
    float a0 = 0.f, a1 = 0.f, a2 = 0.f;

    for (int h = 0; h < 2; ++h) {
        #pragma unroll
        for (int kl = 0; kl < 10; ++kl) {
            int j = jrow[h * 10 + kl];
            const float* up = u + ubase + (size_t)j * 192 + lane * 3;
            float q0 = up[0] + v0, q1 = up[1] + v1, q2 = up[2] + v2;
            float nrm = sqrtf(q0 * q0 + q1 * q1 + q2 * q2) + VN_EPS;
            float f = (gso * nrm + bso) / nrm;
            q0 *= f; q1 *= f; q2 *= f;
            union { _Float16 f16; unsigned short u16; } c0, c1, c2;
            c0.f16 = (_Float16)q0; c1.f16 = (_Float16)q1; c2.f16 = (_Float16)q2;
            Qw[(3 * kl + 0) * 72 + lane] = c0.u16;
            Qw[(3 * kl + 1) * 72 + lane] = c1.u16;
            Qw[(3 * kl + 2) * 72 + lane] = c2.u16;
        }
        WAVESYNC();
        f32x16 acc[2];
        #pragma unroll
        for (int ct = 0; ct < 2; ++ct)
            #pragma unroll
            for (int e = 0; e < 16; ++e) acc[ct][e] = 0.f;
        #pragma unroll
        for (int ks = 0; ks < 4; ++ks) {
            f16x8 af = *(const f16x8*)&Qw[l31 * 72 + ks * 16 + hi * 8];
            acc[0] = __builtin_amdgcn_mfma_f32_32x32x16_f16(af, Bf[0][ks], acc[0], 0, 0, 0);
            acc[1] = __builtin_amdgcn_mfma_f32_32x32x16_f16(af, Bf[1][ks], acc[1], 0, 0, 0);
        }
        #pragma unroll
        for (int ct = 0; ct < 2; ++ct)
            #pragma unroll
            for (int q = 0; q < 4; ++q)
                #pragma unroll
                for (int r = 0; r < 4; ++r) {
                    int row = 4 * hi + 8 * q + r;
                    if (row < 30) Dw[row * 64 + ct * 32 + l31] = acc[ct][q * 4 + r];
                }
        WAVESYNC();
        #pragma unroll
        for (int kl = 0; kl < 10; ++kl) {
            float qd[3], dd[3];
            #pragma unroll
            for (int d = 0; d < 3; ++d) {
                union { unsigned short u16; _Float16 f16; } rr;
                rr.u16 = Qw[(3 * kl + d) * 72 + lane];
                qd[d] = (float)rr.f16;
                dd[d] = Dw[(3 * kl + d) * 64 + lane];
            }
            float dot = qd[0] * dd[0] + qd[1] * dd[1] + qd[2] * dd[2];
            float dn = dd[0] * dd[0] + dd[1] * dd[1] + dd[2] * dd[2];
            float coef = (dot >= 0.f) ? 0.f : 0.8f * dot / (dn + VN_EPS);
            a0 += qd[0] - coef * dd[0];
            a1 += qd[1] - coef * dd[1];
            a2 += qd[2] - coef * dd[2];
        }
        WAVESYNC();
    }
    float s = 1.f / (float)KNN;
    size_t ob = ((size_t)(b * 64 + lane) * 3) * NPTS + n;
    out[ob] = a0 * s;
    out[ob + NPTS] = a1 * s;
    out[ob + 2 * NPTS] = a2 * s;
}

// ---------------- host ----------------
extern "C" void kernel_launch(void* const* d_in, const int* in_sizes, int n_in,
                              void* d_out, int out_size, void* d_ws, size_t ws_size,
                              hipStream_t stream) {
    const float* x = (const float*)d_in[0];
    const float* W1 = (const float*)d_in[1];
    const float* Wd = (const float*)d_in[2];
    const float* gamma = (const float*)d_in[3];
    const float* beta = (const float*)d_in[4];
    float* out = (float*)d_out;

    char* ws = (char*)d_ws;
    size_t off = 0;
    auto alloc = [&](size_t bytes) {
        void* p = ws + off;
        off = (off + bytes + 255) & ~(size_t)255;
        return p;
    };
    float* xxp = (float*)alloc((size_t)NB * NPTS * 4);
    int* idxp = (int*)alloc((size_t)NB * NPTS * KNN * 4);
    float* up = (float*)alloc((size_t)NB * NPTS * 192 * 4);
    float* vp = (float*)alloc((size_t)NB * NPTS * 192 * 4);
    float* partial = (float*)alloc((size_t)2048 * 128 * 4);
    float* gsbs = (float*)alloc(512);
    unsigned short* xsp = (unsigned short*)alloc((size_t)NB * NPTS * 192 * 2);
    float* candV = (float*)alloc((size_t)NB * NPTS * CROW * 4);
    int* candC = (int*)alloc((size_t)NB * NPTS * CROW * 4);

    const int totalRows = NB * NPTS;                 // 16384

    k_prep<<<totalRows / 256, 256, 0, stream>>>(x, xxp, xsp);

    dim3 gd(totalRows / 128, NPTS / 256);            // (128, 32)
    k_distc<<<gd, 256, 0, stream>>>(xsp, xxp, candV, candC);
    k_mrg<<<totalRows / 4, 256, 0, stream>>>(candV, candC, idxp);

    k_uv<<<totalRows / 16, 256, 0, stream>>>(x, W1, up, vp);
    k_stats<<<totalRows / 8, 256, 0, stream>>>(up, vp, idxp, partial);
    k_reduce<<<64, 256, 0, stream>>>(partial, gamma, beta, gsbs);
    k_final<<<totalRows / 4, 256, 0, stream>>>(up, vp, idxp, Wd, gsbs, out);
}

// Round 10
// 767.056 us; speedup vs baseline: 2.0187x; 2.0187x over previous
//
#include <hip/hip_runtime.h>
#include <math.h>

#define NPTS 8192
#define NB 2
#define FDIM 96
#define KNN 20
#define VN_EPS 1e-6f
#define VN_BN_EPS 1e-5f

typedef float f32x16 __attribute__((ext_vector_type(16)));
typedef float f32x4 __attribute__((ext_vector_type(4)));
typedef _Float16 f16x8 __attribute__((ext_vector_type(8)));
typedef unsigned short u16x8 __attribute__((ext_vector_type(8)));

// drain LDS ops + compiler barrier (waves independent; no cross-wave sync needed)
#define WAVESYNC()                                            \
    do {                                                      \
        asm volatile("s_waitcnt lgkmcnt(0)" ::: "memory");    \
        __builtin_amdgcn_wave_barrier();                      \
        asm volatile("" ::: "memory");                        \
    } while (0)

// ---------------- Kernel 1: xx = sum_f xf^2  AND  xs = f16 split table ----------------
__global__ __launch_bounds__(256) void k_prep(const float* __restrict__ x,
                                              float* __restrict__ xx,
                                              unsigned short* __restrict__ xs) {
    int m = blockIdx.x * 256 + threadIdx.x;
    int b = m >> 13, n = m & 8191;
    const float* xf = x + (size_t)b * FDIM * NPTS;
    unsigned short* row = xs + (size_t)m * 192;
    float s = 0.f;
    for (int fc = 0; fc < 12; ++fc) {
        u16x8 hv, lv;
        #pragma unroll
        for (int j = 0; j < 8; ++j) {
            float vv = xf[(size_t)(fc * 8 + j) * NPTS + n];
            s += vv * vv;
            _Float16 h = (_Float16)vv;
            float hf = (float)h;
            _Float16 l = (_Float16)(vv - hf);
            union { _Float16 f; unsigned short u; } ch, cl;
            ch.f = h; cl.f = l;
            hv[j] = ch.u; lv[j] = cl.u;
        }
        *(u16x8*)(row + fc * 8) = hv;
        *(u16x8*)(row + 96 + fc * 8) = lv;
    }
    xx[m] = s;
}

// ---------------- Kernel 2: neg-dist via MFMA, 3-pass f16 split ----------------
// pass order hl, hh, lh -> each transition restages only ONE operand.
// dbuf written with NON-TEMPORAL stores: lines stream to HBM/L3 clean instead of
// lingering dirty in per-XCD L2 (consumer k_topk runs on different XCDs).
__global__ __launch_bounds__(512) void k_dist(const unsigned short* __restrict__ xs,
                                              const float* __restrict__ xx,
                                              float* __restrict__ dbuf,
                                              int rowStart) {
    __shared__ __align__(16) unsigned short Asl[256][104];
    __shared__ __align__(16) unsigned short Bsl[256][104];
    __shared__ float sxr[256];
    __shared__ float sxc[256];
    int t = threadIdx.x;
    int row0 = rowStart + blockIdx.x * 256;
    int b = row0 >> 13, n0 = row0 & 8191;
    int m0 = blockIdx.y * 256;
    const unsigned short* xsb = xs + (size_t)b * NPTS * 192;
    int lane = t & 63, wid = t >> 6;
    int wrow = wid >> 2, wcol = wid & 3;
    int l31 = lane & 31, hi = lane >> 5;
    f32x16 acc[4][2];
    #pragma unroll
    for (int rt = 0; rt < 4; ++rt)
        #pragma unroll
        for (int ct = 0; ct < 2; ++ct)
            #pragma unroll
            for (int e = 0; e < 16; ++e) acc[rt][ct][e] = 0.f;

    int sp = t >> 1, sh = t & 1;
    auto stageA = [&](int part) {
        const unsigned short* sa = xsb + (size_t)(n0 + sp) * 192 + part * 96 + sh * 48;
        unsigned short* da = &Asl[sp][sh * 48];
        #pragma unroll
        for (int j = 0; j < 6; ++j) *(u16x8*)(da + j * 8) = *(const u16x8*)(sa + j * 8);
    };
    auto stageB = [&](int part) {
        const unsigned short* sb = xsb + (size_t)(m0 + sp) * 192 + part * 96 + sh * 48;
        unsigned short* db = &Bsl[sp][sh * 48];
        #pragma unroll
        for (int j = 0; j < 6; ++j) *(u16x8*)(db + j * 8) = *(const u16x8*)(sb + j * 8);
    };
    auto mmpass = [&]() {
        #pragma unroll
        for (int ks = 0; ks < 6; ++ks) {
            f16x8 af[4], bfr[2];
            #pragma unroll
            for (int rt = 0; rt < 4; ++rt)
                af[rt] = *(const f16x8*)&Asl[wrow * 128 + rt * 32 + l31][ks * 16 + hi * 8];
            #pragma unroll
            for (int ct = 0; ct < 2; ++ct)
                bfr[ct] = *(const f16x8*)&Bsl[wcol * 64 + ct * 32 + l31][ks * 16 + hi * 8];
            #pragma unroll
            for (int rt = 0; rt < 4; ++rt)
                #pragma unroll
                for (int ct = 0; ct < 2; ++ct)
                    acc[rt][ct] = __builtin_amdgcn_mfma_f32_32x32x16_f16(af[rt], bfr[ct], acc[rt][ct], 0, 0, 0);
        }
    };

    stageA(0); stageB(1);        // Ah, Bl
    __syncthreads();
    mmpass();                    // hA*lB
    __syncthreads();
    stageB(0);                   // Bh
    __syncthreads();
    mmpass();                    // hA*hB
    __syncthreads();
    stageA(1);                   // Al   (B stays hi)
    __syncthreads();
    mmpass();                    // lA*hB

    __syncthreads();
    if (t < 256) sxr[t] = xx[row0 + t];
    else sxc[t - 256] = xx[(b << 13) + m0 + (t - 256)];
    __syncthreads();
    int lrow0 = row0 - rowStart;
    #pragma unroll
    for (int rt = 0; rt < 4; ++rt) {
        #pragma unroll
        for (int ct = 0; ct < 2; ++ct) {
            int colg = wcol * 64 + ct * 32 + l31;
            float xcv = sxc[colg];
            #pragma unroll
            for (int q = 0; q < 4; ++q) {
                int rbase = wrow * 128 + rt * 32 + 4 * hi + 8 * q;
                #pragma unroll
                for (int r = 0; r < 4; ++r) {
                    float valx = 2.f * acc[rt][ct][q * 4 + r] - sxr[rbase + r] - xcv;
                    __builtin_nontemporal_store(
                        valx, &dbuf[(size_t)(lrow0 + rbase + r) * NPTS + m0 + colg]);
                }
            }
        }
    }
}

// ---------------- Kernel 3: top-20, one BLOCK per row, 4 waves x 2048 cols ----------------
// Non-temporal loads (streaming, no reuse). Per wave: 32 vals/lane register-resident,
// 2 groups of 16, taken-mask extraction. One barrier; wave 0 merges 80 candidates.
__global__ __launch_bounds__(256) void k_topk(const float* __restrict__ dbuf,
                                              int* __restrict__ idxOut,
                                              int rowStart) {
    int t = threadIdx.x;
    int lane = t & 63, w = t >> 6;
    int r = blockIdx.x;
    const float* rowp = dbuf + (size_t)r * NPTS + w * 2048;
    int cbase = w * 2048 + lane * 4;
    f32x4 v[8];
    #pragma unroll
    for (int i = 0; i < 8; ++i)
        v[i] = __builtin_nontemporal_load((const f32x4*)&rowp[i * 256 + lane * 4]);

    float gv0 = -3.4e38f, gv1 = -3.4e38f;
    int gc0 = 0x7fffffff, gc1 = 0x7fffffff;
    #pragma unroll
    for (int i = 0; i < 4; ++i) {
        #pragma unroll
        for (int j = 0; j < 4; ++j) {
            float val = v[i][j]; int col = cbase + i * 256 + j;
            if (val > gv0) { gv0 = val; gc0 = col; }
        }
    }
    #pragma unroll
    for (int i = 4; i < 8; ++i) {
        #pragma unroll
        for (int j = 0; j < 4; ++j) {
            float val = v[i][j]; int col = cbase + i * 256 + j;
            if (val > gv1) { gv1 = val; gc1 = col; }
        }
    }

    unsigned mask = 0;
    __shared__ float swv[4][20];
    __shared__ int swi[4][20];

    for (int kk = 0; kk < KNN; ++kk) {
        float rv; int rc;
        if (gv1 > gv0 || (gv1 == gv0 && gc1 < gc0)) { rv = gv1; rc = gc1; }
        else { rv = gv0; rc = gc0; }
        #pragma unroll
        for (int off = 1; off < 64; off <<= 1) {
            float ov = __shfl_xor(rv, off);
            int oc = __shfl_xor(rc, off);
            if (ov > rv || (ov == rv && oc < rc)) { rv = ov; rc = oc; }
        }
        if (lane == 0) { swv[w][kk] = rv; swi[w][kk] = rc; }
        if (((rc >> 2) & 63) == lane) {
            int ihit = (rc & 2047) >> 8;          // 0..7
            int s = ihit * 4 + (rc & 3);          // 0..31
            mask |= 1u << s;
            if (ihit < 4) {
                gv0 = -3.4e38f; gc0 = 0x7fffffff;
                #pragma unroll
                for (int ii = 0; ii < 4; ++ii) {
                    #pragma unroll
                    for (int j = 0; j < 4; ++j) {
                        int s2 = ii * 4 + j;
                        if (!((mask >> s2) & 1u)) {
                            float val = v[ii][j]; int col = cbase + ii * 256 + j;
                            if (val > gv0) { gv0 = val; gc0 = col; }
                        }
                    }
                }
            } else {
                gv1 = -3.4e38f; gc1 = 0x7fffffff;
                #pragma unroll
                for (int ii = 4; ii < 8; ++ii) {
                    #pragma unroll
                    for (int j = 0; j < 4; ++j) {
                        int s2 = ii * 4 + j;
                        if (!((mask >> s2) & 1u)) {
                            float val = v[ii][j]; int col = cbase + ii * 256 + j;
                            if (val > gv1) { gv1 = val; gc1 = col; }
                        }
                    }
                }
            }
        }
    }
    __syncthreads();
    if (w != 0) return;
    // merge 80 candidates: lane holds c0=lane, c1=64+lane (lane<16)
    int w0 = lane / 20, k0 = lane - w0 * 20;
    float cv0 = swv[w0][k0]; int cc0 = swi[w0][k0];
    float cv1 = -3.4e38f; int cc1 = 0x7fffffff;
    if (lane < 16) { cv1 = swv[3][lane + 4]; cc1 = swi[3][lane + 4]; }
    int grow = rowStart + r;
    for (int kk = 0; kk < KNN; ++kk) {
        float rv; int rc;
        if (cv1 > cv0 || (cv1 == cv0 && cc1 < cc0)) { rv = cv1; rc = cc1; }
        else { rv = cv0; rc = cc0; }
        #pragma unroll
        for (int off = 1; off < 64; off <<= 1) {
            float ov = __shfl_xor(rv, off);
            int oc = __shfl_xor(rc, off);
            if (ov > rv || (ov == rv && oc < rc)) { rv = ov; rc = oc; }
        }
        if (lane == 0) idxOut[(size_t)grow * KNN + kk] = rc;
        if (cc0 == rc) { cv0 = -3.4e38f; cc0 = 0x7fffffff; }
        if (cc1 == rc) { cv1 = -3.4e38f; cc1 = 0x7fffffff; }
    }
}

// ---------------- Kernel 4: u = A*x_point, v = (B-A)*x_point ----------------
__global__ __launch_bounds__(256) void k_uv(const float* __restrict__ x,
                                            const float* __restrict__ W1,
                                            float* __restrict__ u,
                                            float* __restrict__ v) {
    __shared__ float sA[64 * 33];
    __shared__ float sV[64 * 33];
    __shared__ float sxf[FDIM * 16];
    int t = threadIdx.x;
    for (int i = t; i < 64 * 32; i += 256) {
        int o = i >> 5, c = i & 31;
        float a = W1[o * 64 + c];
        sA[o * 33 + c] = a;
        sV[o * 33 + c] = W1[o * 64 + 32 + c] - a;
    }
    int p0 = blockIdx.x * 16;
    int b = p0 >> 13, nb = p0 & 8191;
    const float* xf = x + (size_t)b * FDIM * NPTS;
    for (int i = t; i < FDIM * 16; i += 256) {
        int f = i >> 4, p = i & 15;
        sxf[f * 16 + p] = xf[(size_t)f * NPTS + nb + p];
    }
    __syncthreads();
    #pragma unroll
    for (int ii = 0; ii < 4; ++ii) {
        int it = t + 256 * ii;
        int o = it & 63, p = it >> 6;
        float u0 = 0.f, u1 = 0.f, u2 = 0.f, w0 = 0.f, w1 = 0.f, w2 = 0.f;
        #pragma unroll
        for (int c = 0; c < 32; ++c) {
            float a = sA[o * 33 + c];
            float wv = sV[o * 33 + c];
            float x0 = sxf[(c * 3 + 0) * 16 + p];
            float x1 = sxf[(c * 3 + 1) * 16 + p];
            float x2 = sxf[(c * 3 + 2) * 16 + p];
            u0 += a * x0;  u1 += a * x1;  u2 += a * x2;
            w0 += wv * x0; w1 += wv * x1; w2 += wv * x2;
        }
        size_t base = ((size_t)(p0 + p) * 64 + o) * 3;
        u[base] = u0; u[base + 1] = u1; u[base + 2] = u2;
        v[base] = w0; v[base + 1] = w1; v[base + 2] = w2;
    }
}

// ---------------- Kernel 5: BN stats partials ----------------
__global__ __launch_bounds__(256) void k_stats(const float* __restrict__ u,
                                               const float* __restrict__ v,
                                               const int* __restrict__ idx,
                                               float* __restrict__ partial) {
    int blk = blockIdx.x, t = threadIdx.x;
    int o = t & 63, sub = t >> 6;
    int p0 = blk * 8;
    __shared__ float svf[8 * 192];
    __shared__ int sjf[8 * KNN];
    for (int i = t; i < 8 * 192; i += 256) svf[i] = v[(size_t)p0 * 192 + i];
    for (int i = t; i < 8 * KNN; i += 256) sjf[i] = idx[(size_t)p0 * KNN + i];
    __syncthreads();
    float s1 = 0.f, s2 = 0.f;
    for (int p = 0; p < 8; ++p) {
        int gpt = p0 + p;
        size_t ubase = (size_t)(gpt >> 13) * NPTS * 192;
        const float* vp = &svf[p * 192 + o * 3];
        float v0 = vp[0], v1 = vp[1], v2 = vp[2];
        for (int kk = sub; kk < KNN; kk += 4) {
            int j = sjf[p * KNN + kk];
            const float* up = u + ubase + (size_t)j * 192 + o * 3;
            float q0 = up[0] + v0, q1 = up[1] + v1, q2 = up[2] + v2;
            float nrm = sqrtf(q0 * q0 + q1 * q1 + q2 * q2) + VN_EPS;
            s1 += nrm;
            s2 += nrm * nrm;
        }
    }
    __shared__ float r1[256], r2[256];
    r1[t] = s1; r2[t] = s2;
    __syncthreads();
    if (t < 64) {
        float a1 = r1[t] + r1[t + 64] + r1[t + 128] + r1[t + 192];
        float a2 = r2[t] + r2[t + 64] + r2[t + 128] + r2[t + 192];
        partial[(size_t)blk * 128 + t] = a1;
        partial[(size_t)blk * 128 + 64 + t] = a2;
    }
}

// ---------------- Kernel 6: reduce stats -> gs, bs ----------------
__global__ __launch_bounds__(256) void k_reduce(const float* __restrict__ partial,
                                                const float* __restrict__ gamma,
                                                const float* __restrict__ beta,
                                                float* __restrict__ gsbs) {
    int ch = blockIdx.x, t = threadIdx.x;
    float s1 = 0.f, s2 = 0.f;
    for (int i = t; i < 2048; i += 256) {
        s1 += partial[(size_t)i * 128 + ch];
        s2 += partial[(size_t)i * 128 + 64 + ch];
    }
    __shared__ float r1[256], r2[256];
    r1[t] = s1; r2[t] = s2;
    __syncthreads();
    for (int s = 128; s > 0; s >>= 1) {
        if (t < s) { r1[t] += r1[t + s]; r2[t] += r2[t + s]; }
        __syncthreads();
    }
    if (t == 0) {
        const float cnt = (float)(NB * NPTS * KNN);
        float mean = r1[0] / cnt;
        float var = r2[0] / cnt - mean * mean;
        float inv = 1.0f / sqrtf(var + VN_BN_EPS);
        float g = gamma[ch] * inv;
        gsbs[ch] = g;
        gsbs[64 + ch] = beta[ch] - mean * g;
    }
}

// ---------------- Kernel 7: fused BN + VN-LeakyReLU + mean, MFMA matvec ----------------
__global__ __launch_bounds__(256) void k_final(const float* __restrict__ u,
                                               const float* __restrict__ v,
                                               const int* __restrict__ idx,
                                               const float* __restrict__ Wd,
                                               const float* __restrict__ gsbs,
                                               float* __restrict__ out) {
    int t = threadIdx.x;
    int lane = t & 63, w = t >> 6;
    int l31 = lane & 31, hi = lane >> 5;
    int gpt = blockIdx.x * 4 + w;                 // global point b*N+n
    int b = gpt >> 13, n = gpt & 8191;

    __shared__ __align__(16) unsigned short Qls[4][30 * 72];  // f16
    __shared__ __align__(16) float Dls[4][30 * 64];           // f32
    unsigned short* Qw = Qls[w];
    float* Dw = Dls[w];

    f16x8 Bf[2][4];
    #pragma unroll
    for (int ct = 0; ct < 2; ++ct)
        #pragma unroll
        for (int ks = 0; ks < 4; ++ks) {
            const float* wp = Wd + (size_t)(ct * 32 + l31) * 64 + ks * 16 + hi * 8;
            f16x8 f;
            #pragma unroll
            for (int jj = 0; jj < 8; ++jj) f[jj] = (_Float16)wp[jj];
            Bf[ct][ks] = f;
        }

    float gso = gsbs[lane], bso = gsbs[64 + lane];
    size_t vb = (size_t)gpt * 192 + lane * 3;
    float v0 = v[vb], v1 = v[vb + 1], v2 = v[vb + 2];
    const int* jrow = idx + (size_t)gpt * KNN;
    size_t ubase = (size_t)b * NPTS * 192;
    float a0 = 0.f, a1 = 0.f, a2 = 0.f;

    for (int h = 0; h < 2; ++h) {
        #pragma unroll
        for (int kl = 0; kl < 10; ++kl) {
            int j = jrow[h * 10 + kl];
            const float* up = u + ubase + (size_t)j * 192 + lane * 3;
            float q0 = up[0] + v0, q1 = up[1] + v1, q2 = up[2] + v2;
            float nrm = sqrtf(q0 * q0 + q1 * q1 + q2 * q2) + VN_EPS;
            float f = (gso * nrm + bso) / nrm;
            q0 *= f; q1 *= f; q2 *= f;
            union { _Float16 f16; unsigned short u16; } c0, c1, c2;
            c0.f16 = (_Float16)q0; c1.f16 = (_Float16)q1; c2.f16 = (_Float16)q2;
            Qw[(3 * kl + 0) * 72 + lane] = c0.u16;
            Qw[(3 * kl + 1) * 72 + lane] = c1.u16;
            Qw[(3 * kl + 2) * 72 + lane] = c2.u16;
        }
        WAVESYNC();
        f32x16 acc[2];
        #pragma unroll
        for (int ct = 0; ct < 2; ++ct)
            #pragma unroll
            for (int e = 0; e < 16; ++e) acc[ct][e] = 0.f;
        #pragma unroll
        for (int ks = 0; ks < 4; ++ks) {
            f16x8 af = *(const f16x8*)&Qw[l31 * 72 + ks * 16 + hi * 8];
            acc[0] = __builtin_amdgcn_mfma_f32_32x32x16_f16(af, Bf[0][ks], acc[0], 0, 0, 0);
            acc[1] = __builtin_amdgcn_mfma_f32_32x32x16_f16(af, Bf[1][ks], acc[1], 0, 0, 0);
        }
        #pragma unroll
        for (int ct = 0; ct < 2; ++ct)
            #pragma unroll
            for (int q = 0; q < 4; ++q)
                #pragma unroll
                for (int r = 0; r < 4; ++r) {
                    int row = 4 * hi + 8 * q + r;
                    if (row < 30) Dw[row * 64 + ct * 32 + l31] = acc[ct][q * 4 + r];
                }
        WAVESYNC();
        #pragma unroll
        for (int kl = 0; kl < 10; ++kl) {
            float qd[3], dd[3];
            #pragma unroll
            for (int d = 0; d < 3; ++d) {
                union { unsigned short u16; _Float16 f16; } rr;
                rr.u16 = Qw[(3 * kl + d) * 72 + lane];
                qd[d] = (float)rr.f16;
                dd[d] = Dw[(3 * kl + d) * 64 + lane];
            }
            float dot = qd[0] * dd[0] + qd[1] * dd[1] + qd[2] * dd[2];
            float dn = dd[0] * dd[0] + dd[1] * dd[1] + dd[2] * dd[2];
            float coef = (dot >= 0.f) ? 0.f : 0.8f * dot / (dn + VN_EPS);
            a0 += qd[0] - coef * dd[0];
            a1 += qd[1] - coef * dd[1];
            a2 += qd[2] - coef * dd[2];
        }
        WAVESYNC();
    }
    float s = 1.f / (float)KNN;
    size_t ob = ((size_t)(b * 64 + lane) * 3) * NPTS + n;
    out[ob] = a0 * s;
    out[ob + NPTS] = a1 * s;
    out[ob + 2 * NPTS] = a2 * s;
}

// ---------------- host ----------------
extern "C" void kernel_launch(void* const* d_in, const int* in_sizes, int n_in,
                              void* d_out, int out_size, void* d_ws, size_t ws_size,
                              hipStream_t stream) {
    const float* x = (const float*)d_in[0];
    const float* W1 = (const float*)d_in[1];
    const float* Wd = (const float*)d_in[2];
    const float* gamma = (const float*)d_in[3];
    const float* beta = (const float*)d_in[4];
    float* out = (float*)d_out;

    char* ws = (char*)d_ws;
    size_t off = 0;
    auto alloc = [&](size_t bytes) {
        void* p = ws + off;
        off = (off + bytes + 255) & ~(size_t)255;
        return p;
    };
    float* xxp = (float*)alloc((size_t)NB * NPTS * 4);
    int* idxp = (int*)alloc((size_t)NB * NPTS * KNN * 4);
    float* up = (float*)alloc((size_t)NB * NPTS * 192 * 4);
    float* vp = (float*)alloc((size_t)NB * NPTS * 192 * 4);
    float* partial = (float*)alloc((size_t)2048 * 128 * 4);
    float* gsbs = (float*)alloc(512);
    unsigned short* xsp = (unsigned short*)alloc((size_t)NB * NPTS * 192 * 2);
    float* dbuf = (float*)(ws + off);

    const int totalRows = NB * NPTS;                 // 16384
    long avail = (long)ws_size - (long)off;
    long cap_l = avail / ((long)NPTS * 4);
    int cap = (int)((cap_l / 256) * 256);
    if (cap < 256) cap = 256;
    if (cap > 4096) cap = 4096;                      // 128 MB chunk

    k_prep<<<totalRows / 256, 256, 0, stream>>>(x, xxp, xsp);

    for (int start = 0; start < totalRows; start += cap) {
        int rows = totalRows - start;
        if (rows > cap) rows = cap;
        dim3 gg(rows / 256, NPTS / 256);
        k_dist<<<gg, 512, 0, stream>>>(xsp, xxp, dbuf, start);
        k_topk<<<rows, 256, 0, stream>>>(dbuf, idxp, start);
    }

    k_uv<<<totalRows / 16, 256, 0, stream>>>(x, W1, up, vp);
    k_stats<<<totalRows / 8, 256, 0, stream>>>(up, vp, idxp, partial);
    k_reduce<<<64, 256, 0, stream>>>(partial, gamma, beta, gsbs);
    k_final<<<totalRows / 4, 256, 0, stream>>>(up, vp, idxp, Wd, gsbs, out);
}

// Round 11
// 510.931 us; speedup vs baseline: 3.0307x; 1.5013x over previous
//
#include <hip/hip_runtime.h>
#include <math.h>

#define NPTS 8192
#define NB 2
#define FDIM 96
#define KNN 20
#define VN_EPS 1e-6f
#define VN_BN_EPS 1e-5f

typedef float f32x16 __attribute__((ext_vector_type(16)));
typedef _Float16 f16x8 __attribute__((ext_vector_type(8)));
typedef unsigned short u16x8 __attribute__((ext_vector_type(8)));

// drain LDS ops + compiler barrier (waves independent; no cross-wave sync needed)
#define WAVESYNC()                                            \
    do {                                                      \
        asm volatile("s_waitcnt lgkmcnt(0)" ::: "memory");    \
        __builtin_amdgcn_wave_barrier();                      \
        asm volatile("" ::: "memory");                        \
    } while (0)

// ---------------- Kernel 1: xx = sum_f xf^2  AND  xs = f16 split table ----------------
__global__ __launch_bounds__(256) void k_prep(const float* __restrict__ x,
                                              float* __restrict__ xx,
                                              unsigned short* __restrict__ xs) {
    int m = blockIdx.x * 256 + threadIdx.x;
    int b = m >> 13, n = m & 8191;
    const float* xf = x + (size_t)b * FDIM * NPTS;
    unsigned short* row = xs + (size_t)m * 192;
    float s = 0.f;
    for (int fc = 0; fc < 12; ++fc) {
        u16x8 hv, lv;
        #pragma unroll
        for (int j = 0; j < 8; ++j) {
            float vv = xf[(size_t)(fc * 8 + j) * NPTS + n];
            s += vv * vv;
            _Float16 h = (_Float16)vv;
            float hf = (float)h;
            _Float16 l = (_Float16)(vv - hf);
            union { _Float16 f; unsigned short u; } ch, cl;
            ch.f = h; cl.f = l;
            hv[j] = ch.u; lv[j] = cl.u;
        }
        *(u16x8*)(row + fc * 8) = hv;
        *(u16x8*)(row + 96 + fc * 8) = lv;
    }
    xx[m] = s;
}

// ---------------- Kernel 2: neg-dist via MFMA, 3-pass f16 split ----------------
__global__ __launch_bounds__(512) void k_dist(const unsigned short* __restrict__ xs,
                                              const float* __restrict__ xx,
                                              float* __restrict__ dbuf,
                                              int rowStart) {
    __shared__ __align__(16) unsigned short Asl[256][104];
    __shared__ __align__(16) unsigned short Bsl[256][104];
    __shared__ float sxr[256];
    __shared__ float sxc[256];
    int t = threadIdx.x;
    int row0 = rowStart + blockIdx.x * 256;
    int b = row0 >> 13, n0 = row0 & 8191;
    int m0 = blockIdx.y * 256;
    const unsigned short* xsb = xs + (size_t)b * NPTS * 192;
    int lane = t & 63, wid = t >> 6;
    int wrow = wid >> 2, wcol = wid & 3;
    int l31 = lane & 31, hi = lane >> 5;
    f32x16 acc[4][2];
    #pragma unroll
    for (int rt = 0; rt < 4; ++rt)
        #pragma unroll
        for (int ct = 0; ct < 2; ++ct)
            #pragma unroll
            for (int e = 0; e < 16; ++e) acc[rt][ct][e] = 0.f;

    int sp = t >> 1, sh = t & 1;
    auto stageA = [&](int part) {
        const unsigned short* sa = xsb + (size_t)(n0 + sp) * 192 + part * 96 + sh * 48;
        unsigned short* da = &Asl[sp][sh * 48];
        #pragma unroll
        for (int j = 0; j < 6; ++j) *(u16x8*)(da + j * 8) = *(const u16x8*)(sa + j * 8);
    };
    auto stageB = [&](int part) {
        const unsigned short* sb = xsb + (size_t)(m0 + sp) * 192 + part * 96 + sh * 48;
        unsigned short* db = &Bsl[sp][sh * 48];
        #pragma unroll
        for (int j = 0; j < 6; ++j) *(u16x8*)(db + j * 8) = *(const u16x8*)(sb + j * 8);
    };
    auto mmpass = [&]() {
        #pragma unroll
        for (int ks = 0; ks < 6; ++ks) {
            f16x8 af[4], bfr[2];
            #pragma unroll
            for (int rt = 0; rt < 4; ++rt)
                af[rt] = *(const f16x8*)&Asl[wrow * 128 + rt * 32 + l31][ks * 16 + hi * 8];
            #pragma unroll
            for (int ct = 0; ct < 2; ++ct)
                bfr[ct] = *(const f16x8*)&Bsl[wcol * 64 + ct * 32 + l31][ks * 16 + hi * 8];
            #pragma unroll
            for (int rt = 0; rt < 4; ++rt)
                #pragma unroll
                for (int ct = 0; ct < 2; ++ct)
                    acc[rt][ct] = __builtin_amdgcn_mfma_f32_32x32x16_f16(af[rt], bfr[ct], acc[rt][ct], 0, 0, 0);
        }
    };

    stageA(0); stageB(1);        // Ah, Bl
    __syncthreads();
    mmpass();                    // hA*lB
    __syncthreads();
    stageB(0);                   // Bh
    __syncthreads();
    mmpass();                    // hA*hB
    __syncthreads();
    stageA(1);                   // Al   (B stays hi)
    __syncthreads();
    mmpass();                    // lA*hB

    __syncthreads();
    if (t < 256) sxr[t] = xx[row0 + t];
    else sxc[t - 256] = xx[(b << 13) + m0 + (t - 256)];
    __syncthreads();
    int lrow0 = row0 - rowStart;
    #pragma unroll
    for (int rt = 0; rt < 4; ++rt) {
        #pragma unroll
        for (int ct = 0; ct < 2; ++ct) {
            int colg = wcol * 64 + ct * 32 + l31;
            float xcv = sxc[colg];
            #pragma unroll
            for (int q = 0; q < 4; ++q) {
                int rbase = wrow * 128 + rt * 32 + 4 * hi + 8 * q;
                #pragma unroll
                for (int r = 0; r < 4; ++r) {
                    float valx = 2.f * acc[rt][ct][q * 4 + r] - sxr[rbase + r] - xcv;
                    dbuf[(size_t)(lrow0 + rbase + r) * NPTS + m0 + colg] = valx;
                }
            }
        }
    }
}

// ---------------- Kernel 3: top-20 via count-based threshold select ----------------
// One block per row. 32 orderable keys/thread in registers. 16-iteration bisection on
// the top-16-bit prefix (register compares + wave reduce; no histograms, no serial
// extraction chains). Survivors (>= threshold prefix, superset of exact top-20) are
// ranked all-pairs with exact (val desc, col asc) tie-break = lax.top_k order.
__global__ __launch_bounds__(256) void k_topk(const float* __restrict__ dbuf,
                                              int* __restrict__ idxOut,
                                              int rowStart) {
    int t = threadIdx.x;
    int lane = t & 63, w = t >> 6;
    int r = blockIdx.x;
    const float* rowp = dbuf + (size_t)r * NPTS;

    // load 32 values, convert to orderable keys (monotonic bijection f32 -> u32)
    unsigned key[32];
    #pragma unroll
    for (int i = 0; i < 32; ++i) {
        unsigned u = __float_as_uint(rowp[i * 256 + t]);
        key[i] = (u & 0x80000000u) ? ~u : (u | 0x80000000u);
    }

    __shared__ int swsum[4];
    __shared__ int scnt;
    __shared__ unsigned sk[256];
    __shared__ int sc[256];
    if (t == 0) scnt = 0;

    // bisect largest 16-bit prefix P with count(key >= P<<16) >= KNN
    unsigned lo = 0, hi = 0x10000u;
    for (int iter = 0; iter < 16; ++iter) {
        unsigned mid = (lo + hi) >> 1;
        unsigned mkey = mid << 16;
        int c = 0;
        #pragma unroll
        for (int i = 0; i < 32; ++i) c += (key[i] >= mkey) ? 1 : 0;
        #pragma unroll
        for (int d = 1; d < 64; d <<= 1) c += __shfl_xor(c, d);
        if (lane == 0) swsum[w] = c;
        __syncthreads();
        int tot = swsum[0] + swsum[1] + swsum[2] + swsum[3];
        if (tot >= KNN) lo = mid; else hi = mid;
        __syncthreads();
    }
    unsigned thr = lo << 16;

    // collect survivors (count >= KNN by invariant; typically ~20-60)
    #pragma unroll
    for (int i = 0; i < 32; ++i) {
        if (key[i] >= thr) {
            int j = atomicAdd(&scnt, 1);
            if (j < 256) { sk[j] = key[i]; sc[j] = i * 256 + t; }
        }
    }
    __syncthreads();
    int nc = scnt; if (nc > 256) nc = 256;
    int grow = rowStart + r;
    if (t < nc) {
        unsigned kv = sk[t];
        int cv = sc[t];
        int rank = 0;
        for (int j = 0; j < nc; ++j) {
            unsigned kj = sk[j];
            int cj = sc[j];
            rank += (kj > kv || (kj == kv && cj < cv)) ? 1 : 0;
        }
        if (rank < KNN) idxOut[(size_t)grow * KNN + rank] = cv;
    }
}

// ---------------- Kernel 4: u = A*x_point, v = (B-A)*x_point ----------------
__global__ __launch_bounds__(256) void k_uv(const float* __restrict__ x,
                                            const float* __restrict__ W1,
                                            float* __restrict__ u,
                                            float* __restrict__ v) {
    __shared__ float sA[64 * 33];
    __shared__ float sV[64 * 33];
    __shared__ float sxf[FDIM * 16];
    int t = threadIdx.x;
    for (int i = t; i < 64 * 32; i += 256) {
        int o = i >> 5, c = i & 31;
        float a = W1[o * 64 + c];
        sA[o * 33 + c] = a;
        sV[o * 33 + c] = W1[o * 64 + 32 + c] - a;
    }
    int p0 = blockIdx.x * 16;
    int b = p0 >> 13, nb = p0 & 8191;
    const float* xf = x + (size_t)b * FDIM * NPTS;
    for (int i = t; i < FDIM * 16; i += 256) {
        int f = i >> 4, p = i & 15;
        sxf[f * 16 + p] = xf[(size_t)f * NPTS + nb + p];
    }
    __syncthreads();
    #pragma unroll
    for (int ii = 0; ii < 4; ++ii) {
        int it = t + 256 * ii;
        int o = it & 63, p = it >> 6;
        float u0 = 0.f, u1 = 0.f, u2 = 0.f, w0 = 0.f, w1 = 0.f, w2 = 0.f;
        #pragma unroll
        for (int c = 0; c < 32; ++c) {
            float a = sA[o * 33 + c];
            float wv = sV[o * 33 + c];
            float x0 = sxf[(c * 3 + 0) * 16 + p];
            float x1 = sxf[(c * 3 + 1) * 16 + p];
            float x2 = sxf[(c * 3 + 2) * 16 + p];
            u0 += a * x0;  u1 += a * x1;  u2 += a * x2;
            w0 += wv * x0; w1 += wv * x1; w2 += wv * x2;
        }
        size_t base = ((size_t)(p0 + p) * 64 + o) * 3;
        u[base] = u0; u[base + 1] = u1; u[base + 2] = u2;
        v[base] = w0; v[base + 1] = w1; v[base + 2] = w2;
    }
}

// ---------------- Kernel 5: BN stats partials ----------------
__global__ __launch_bounds__(256) void k_stats(const float* __restrict__ u,
                                               const float* __restrict__ v,
                                               const int* __restrict__ idx,
                                               float* __restrict__ partial) {
    int blk = blockIdx.x, t = threadIdx.x;
    int o = t & 63, sub = t >> 6;
    int p0 = blk * 8;
    __shared__ float svf[8 * 192];
    __shared__ int sjf[8 * KNN];
    for (int i = t; i < 8 * 192; i += 256) svf[i] = v[(size_t)p0 * 192 + i];
    for (int i = t; i < 8 * KNN; i += 256) sjf[i] = idx[(size_t)p0 * KNN + i];
    __syncthreads();
    float s1 = 0.f, s2 = 0.f;
    for (int p = 0; p < 8; ++p) {
        int gpt = p0 + p;
        size_t ubase = (size_t)(gpt >> 13) * NPTS * 192;
        const float* vp = &svf[p * 192 + o * 3];
        float v0 = vp[0], v1 = vp[1], v2 = vp[2];
        for (int kk = sub; kk < KNN; kk += 4) {
            int j = sjf[p * KNN + kk];
            const float* up = u + ubase + (size_t)j * 192 + o * 3;
            float q0 = up[0] + v0, q1 = up[1] + v1, q2 = up[2] + v2;
            float nrm = sqrtf(q0 * q0 + q1 * q1 + q2 * q2) + VN_EPS;
            s1 += nrm;
            s2 += nrm * nrm;
        }
    }
    __shared__ float r1[256], r2[256];
    r1[t] = s1; r2[t] = s2;
    __syncthreads();
    if (t < 64) {
        float a1 = r1[t] + r1[t + 64] + r1[t + 128] + r1[t + 192];
        float a2 = r2[t] + r2[t + 64] + r2[t + 128] + r2[t + 192];
        partial[(size_t)blk * 128 + t] = a1;
        partial[(size_t)blk * 128 + 64 + t] = a2;
    }
}

// ---------------- Kernel 6: reduce stats -> gs, bs ----------------
__global__ __launch_bounds__(256) void k_reduce(const float* __restrict__ partial,
                                                const float* __restrict__ gamma,
                                                const float* __restrict__ beta,
                                                float* __restrict__ gsbs) {
    int ch = blockIdx.x, t = threadIdx.x;
    float s1 = 0.f, s2 = 0.f;
    for (int i = t; i < 2048; i += 256) {
        s1 += partial[(size_t)i * 128 + ch];
        s2 += partial[(size_t)i * 128 + 64 + ch];
    }
    __shared__ float r1[256], r2[256];
    r1[t] = s1; r2[t] = s2;
    __syncthreads();
    for (int s = 128; s > 0; s >>= 1) {
        if (t < s) { r1[t] += r1[t + s]; r2[t] += r2[t + s]; }
        __syncthreads();
    }
    if (t == 0) {
        const float cnt = (float)(NB * NPTS * KNN);
        float mean = r1[0] / cnt;
        float var = r2[0] / cnt - mean * mean;
        float inv = 1.0f / sqrtf(var + VN_BN_EPS);
        float g = gamma[ch] * inv;
        gsbs[ch] = g;
        gsbs[64 + ch] = beta[ch] - mean * g;
    }
}

// ---------------- Kernel 7: fused BN + VN-LeakyReLU + mean, MFMA matvec ----------------
__global__ __launch_bounds__(256) void k_final(const float* __restrict__ u,
                                               const float* __restrict__ v,
                                               const int* __restrict__ idx,
                                               const float* __restrict__ Wd,
                                               const float* __restrict__ gsbs,
                                               float* __restrict__ out) {
    int t = threadIdx.x;
    int lane = t & 63, w = t >> 6;
    int l31 = lane & 31, hi = lane >> 5;
    int gpt = blockIdx.x * 4 + w;                 // global point b*N+n
    int b = gpt >> 13, n = gpt & 8191;

    __shared__ __align__(16) unsigned short Qls[4][30 * 72];  // f16
    __shared__ __align__(16) float Dls[4][30 * 64];           // f32
    unsigned short* Qw = Qls[w];
    float* Dw = Dls[w];

    f16x8 Bf[2][4];
    #pragma unroll
    for (int ct = 0; ct < 2; ++ct)
        #pragma unroll
        for (int ks = 0; ks < 4; ++ks) {
            const float* wp = Wd + (size_t)(ct * 32 + l31) * 64 + ks * 16 + hi * 8;
            f16x8 f;
            #pragma unroll
            for (int jj = 0; jj < 8; ++jj) f[jj] = (_Float16)wp[jj];
            Bf[ct][ks] = f;
        }

    float gso = gsbs[lane], bso = gsbs[64 + lane];
    size_t vb = (size_t)gpt * 192 + lane * 3;
    float v0 = v[vb], v1 = v[vb + 1], v2 = v[vb + 2];
    const int* jrow = idx + (size_t)gpt * KNN;
    size_t ubase = (size_t)b * NPTS * 192;
    float a0 = 0.f, a1 = 0.f, a2 = 0.f;

    for (int h = 0; h < 2; ++h) {
        #pragma unroll
        for (int kl = 0; kl < 10; ++kl) {
            int j = jrow[h * 10 + kl];
            const float* up = u + ubase + (size_t)j * 192 + lane * 3;
            float q0 = up[0] + v0, q1 = up[1] + v1, q2 = up[2] + v2;
            float nrm = sqrtf(q0 * q0 + q1 * q1 + q2 * q2) + VN_EPS;
            float f = (gso * nrm + bso) / nrm;
            q0 *= f; q1 *= f; q2 *= f;
            union { _Float16 f16; unsigned short u16; } c0, c1, c2;
            c0.f16 = (_Float16)q0; c1.f16 = (_Float16)q1; c2.f16 = (_Float16)q2;
            Qw[(3 * kl + 0) * 72 + lane] = c0.u16;
            Qw[(3 * kl + 1) * 72 + lane] = c1.u16;
            Qw[(3 * kl + 2) * 72 + lane] = c2.u16;
        }
        WAVESYNC();
        f32x16 acc[2];
        #pragma unroll
        for (int ct = 0; ct < 2; ++ct)
            #pragma unroll
            for (int e = 0; e < 16; ++e) acc[ct][e] = 0.f;
        #pragma unroll
        for (int ks = 0; ks < 4; ++ks) {
            f16x8 af = *(const f16x8*)&Qw[l31 * 72 + ks * 16 + hi * 8];
            acc[0] = __builtin_amdgcn_mfma_f32_32x32x16_f16(af, Bf[0][ks], acc[0], 0, 0, 0);
            acc[1] = __builtin_amdgcn_mfma_f32_32x32x16_f16(af, Bf[1][ks], acc[1], 0, 0, 0);
        }
        #pragma unroll
        for (int ct = 0; ct < 2; ++ct)
            #pragma unroll
            for (int q = 0; q < 4; ++q)
                #pragma unroll
                for (int r = 0; r < 4; ++r) {
                    int row = 4 * hi + 8 * q + r;
                    if (row < 30) Dw[row * 64 + ct * 32 + l31] = acc[ct][q * 4 + r];
                }
        WAVESYNC();
        #pragma unroll
        for (int kl = 0; kl < 10; ++kl) {
            float qd[3], dd[3];
            #pragma unroll
            for (int d = 0; d < 3; ++d) {
                union { unsigned short u16; _Float16 f16; } rr;
                rr.u16 = Qw[(3 * kl + d) * 72 + lane];
                qd[d] = (float)rr.f16;
                dd[d] = Dw[(3 * kl + d) * 64 + lane];
            }
            float dot = qd[0] * dd[0] + qd[1] * dd[1] + qd[2] * dd[2];
            float dn = dd[0] * dd[0] + dd[1] * dd[1] + dd[2] * dd[2];
            float coef = (dot >= 0.f) ? 0.f : 0.8f * dot / (dn + VN_EPS);
            a0 += qd[0] - coef * dd[0];
            a1 += qd[1] - coef * dd[1];
            a2 += qd[2] - coef * dd[2];
        }
        WAVESYNC();
    }
    float s = 1.f / (float)KNN;
    size_t ob = ((size_t)(b * 64 + lane) * 3) * NPTS + n;
    out[ob] = a0 * s;
    out[ob + NPTS] = a1 * s;
    out[ob + 2 * NPTS] = a2 * s;
}

// ---------------- host ----------------
extern "C" void kernel_launch(void* const* d_in, const int* in_sizes, int n_in,
                              void* d_out, int out_size, void* d_ws, size_t ws_size,
                              hipStream_t stream) {
    const float* x = (const float*)d_in[0];
    const float* W1 = (const float*)d_in[1];
    const float* Wd = (const float*)d_in[2];
    const float* gamma = (const float*)d_in[3];
    const float* beta = (const float*)d_in[4];
    float* out = (float*)d_out;

    char* ws = (char*)d_ws;
    size_t off = 0;
    auto alloc = [&](size_t bytes) {
        void* p = ws + off;
        off = (off + bytes + 255) & ~(size_t)255;
        return p;
    };
    float* xxp = (float*)alloc((size_t)NB * NPTS * 4);
    int* idxp = (int*)alloc((size_t)NB * NPTS * KNN * 4);
    float* up = (float*)alloc((size_t)NB * NPTS * 192 * 4);
    float* vp = (float*)alloc((size_t)NB * NPTS * 192 * 4);
    float* partial = (float*)alloc((size_t)2048 * 128 * 4);
    float* gsbs = (float*)alloc(512);
    unsigned short* xsp = (unsigned short*)alloc((size_t)NB * NPTS * 192 * 2);
    float* dbuf = (float*)(ws + off);

    const int totalRows = NB * NPTS;                 // 16384
    long avail = (long)ws_size - (long)off;
    long cap_l = avail / ((long)NPTS * 4);
    int cap = (int)((cap_l / 256) * 256);
    if (cap < 256) cap = 256;
    if (cap > 4096) cap = 4096;                      // 128 MB chunk

    k_prep<<<totalRows / 256, 256, 0, stream>>>(x, xxp, xsp);

    for (int start = 0; start < totalRows; start += cap) {
        int rows = totalRows - start;
        if (rows > cap) rows = cap;
        dim3 gg(rows / 256, NPTS / 256);
        k_dist<<<gg, 512, 0, stream>>>(xsp, xxp, dbuf, start);
        k_topk<<<rows, 256, 0, stream>>>(dbuf, idxp, start);
    }

    k_uv<<<totalRows / 16, 256, 0, stream>>>(x, W1, up, vp);
    k_stats<<<totalRows / 8, 256, 0, stream>>>(up, vp, idxp, partial);
    k_reduce<<<64, 256, 0, stream>>>(partial, gamma, beta, gsbs);
    k_final<<<totalRows / 4, 256, 0, stream>>>(up, vp, idxp, Wd, gsbs, out);
}